// Round 2
// baseline (2112.435 us; speedup 1.0000x reference)
//
#include <hip/hip_runtime.h>
#include <hip/hip_bf16.h>

#define B_ 2
#define C_ 64
#define H_ 128
#define W_ 128
#define HS 64
#define WS 64
#define L_ 4096
#define S_ 4096
#define K1_ 576    // C*3*3
#define NCOL 1024  // C*4*4
#define SCALE_ 10.0f

// transposed flat index within a 64x64 grid
__device__ __forceinline__ int TT(int x) { return ((x & 63) << 6) | (x >> 6); }

// fused diag_prop -> T -> diag_prop -> T, evaluated pointwise from raw scores
__device__ __forceinline__ float diag9(const float* __restrict__ inb, int l, int s) {
    int tl = TT(l), ts = TT(s);
    float acc = 0.f;
#pragma unroll
    for (int d2 = -1; d2 <= 1; ++d2) {
        int p = tl + d2, q = ts + d2;
        if (p < 0 || p >= 4096 || q < 0 || q >= 4096) continue;
        int l2 = TT(p), s2 = TT(q);
#pragma unroll
        for (int d1 = -1; d1 <= 1; ++d1) {
            int a = l2 + d1, c2 = s2 + d1;
            if (a >= 0 && a < 4096 && c2 >= 0 && c2 < 4096) acc += inb[((size_t)a << 12) + c2];
        }
    }
    return acc;
}

// ---------------- K0a: downsample fg/bg/mask by 2 ----------------
__global__ void k_downsample(const float* __restrict__ fg, const float* __restrict__ bg,
                             const float* __restrict__ mask,
                             float* __restrict__ fg_ds, float* __restrict__ bg_ds,
                             float* __restrict__ m_ds) {
    int idx = blockIdx.x * 256 + threadIdx.x;  // over B*C*64*64
    if (idx >= B_ * C_ * HS * WS) return;
    int j = idx & 63, i = (idx >> 6) & 63, c = (idx >> 12) & 63, b = idx >> 18;
    int src = ((b * C_ + c) * H_ + 2 * i) * W_ + 2 * j;
    fg_ds[idx] = fg[src];
    bg_ds[idx] = bg[src];
    if (c == 0) m_ds[(b * HS + i) * WS + j] = mask[(b * H_ + 2 * i) * W_ + 2 * j];
}

// ---------------- K0b: per-patch mask flag + 1/denom ----------------
__global__ void k_patch_stats(const float* __restrict__ bg_ds, const float* __restrict__ m_ds,
                              float* __restrict__ denom_inv, float* __restrict__ maskedf) {
    int idx = blockIdx.x * 256 + threadIdx.x;  // B*L
    if (idx >= B_ * L_) return;
    int b = idx >> 12, l = idx & 4095, lh = l >> 6, lw = l & 63;
    float msum = 0.f;
    for (int di = -1; di <= 1; ++di)
        for (int dj = -1; dj <= 1; ++dj) {
            int i = lh + di, j = lw + dj;
            if (i >= 0 && i < HS && j >= 0 && j < WS) msum += m_ds[(b * HS + i) * WS + j];
        }
    maskedf[idx] = (msum == 0.0f) ? 1.0f : 0.0f;
    float ss = 0.f;
    for (int c = 0; c < C_; ++c)
        for (int di = -1; di <= 1; ++di)
            for (int dj = -1; dj <= 1; ++dj) {
                int i = lh + di, j = lw + dj;
                if (i >= 0 && i < HS && j >= 0 && j < WS) {
                    float v = bg_ds[((b * C_ + c) * HS + i) * WS + j];
                    ss += v * v;
                }
            }
    denom_inv[idx] = 1.0f / fmaxf(sqrtf(ss), 0.001f);
}

// ---------------- K1: scores GEMM (implicit im2col both sides) ----------------
// scores[b,l,s] = denom_inv[b,l] * sum_k bgpatch[l,k] * fgpatch[s,k]
__global__ __launch_bounds__(256) void k_gemm1(const float* __restrict__ fg_ds,
                                               const float* __restrict__ bg_ds,
                                               const float* __restrict__ denom_inv,
                                               float* __restrict__ out) {
    __shared__ float As[16][64];
    __shared__ float Bs[16][64];
    int t = threadIdx.x;
    int tx = t & 15, ty = t >> 4;
    int sh = blockIdx.x, lh = blockIdx.y, b = blockIdx.z;
    int kk = t >> 4, col0 = (t & 15) * 4;
    const float* bgb = bg_ds + b * C_ * HS * WS;
    const float* fgb = fg_ds + b * C_ * HS * WS;
    float acc[4][4] = {};
    for (int kt = 0; kt < K1_; kt += 16) {
        int k = kt + kk;
        int c = k / 9, r = k - 9 * c;
        int di = r / 3 - 1, dj = r - 3 * (r / 3) - 1;
        int ia = lh + di, ib = sh + di;
        const float* arow = bgb + (c * HS + ia) * WS;
        const float* brow = fgb + (c * HS + ib) * WS;
        bool iaok = (ia >= 0 && ia < HS), ibok = (ib >= 0 && ib < HS);
#pragma unroll
        for (int u = 0; u < 4; ++u) {
            int ja = col0 + u + dj;
            bool jok = (ja >= 0 && ja < WS);
            As[kk][col0 + u] = (iaok && jok) ? arow[ja] : 0.f;
            Bs[kk][col0 + u] = (ibok && jok) ? brow[ja] : 0.f;
        }
        __syncthreads();
#pragma unroll
        for (int kki = 0; kki < 16; ++kki) {
            float a[4], bb[4];
#pragma unroll
            for (int i = 0; i < 4; ++i) a[i] = As[kki][ty * 4 + i];
#pragma unroll
            for (int j = 0; j < 4; ++j) bb[j] = Bs[kki][tx * 4 + j];
#pragma unroll
            for (int i = 0; i < 4; ++i)
#pragma unroll
                for (int j = 0; j < 4; ++j) acc[i][j] = fmaf(a[i], bb[j], acc[i][j]);
        }
        __syncthreads();
    }
    int s0 = sh * 64 + tx * 4;
#pragma unroll
    for (int i = 0; i < 4; ++i) {
        int l = lh * 64 + ty * 4 + i;
        float dinv = denom_inv[b * L_ + l];
        size_t base = ((size_t)(b * L_ + l) << 12) + s0;
#pragma unroll
        for (int j = 0; j < 4; ++j) out[base + j] = acc[i][j] * dinv;
    }
}

// ---------------- K3a: chunked online-softmax partials over l (diag fused) ----------------
__global__ __launch_bounds__(256) void k_soft_part(const float* __restrict__ scores,
                                                   const float* __restrict__ maskedf,
                                                   float* __restrict__ pm, float* __restrict__ pz) {
    __shared__ float sm[256], sz[256];
    int t = threadIdx.x;
    int tx = t & 63, tyy = t >> 6;
    int sg = blockIdx.x, ch = blockIdx.y, b = blockIdx.z;
    int s = sg * 64 + tx;
    const float* inb = scores + ((size_t)b << 24);
    const float* mk = maskedf + b * L_;
    float m = -3.0e38f, Z = 0.f;
    int l0 = ch * 512 + tyy;
    for (int ii = 0; ii < 128; ++ii) {
        int l = l0 + 4 * ii;
        float v = (mk[l] != 0.f) ? -1000.f : diag9(inb, l, s);
        float mn = fmaxf(m, v);
        Z = Z * __expf(SCALE_ * (m - mn)) + __expf(SCALE_ * (v - mn));
        m = mn;
    }
    sm[t] = m;
    sz[t] = Z;
    __syncthreads();
    if (t < 64) {
        float gm = sm[t], gz = sz[t];
#pragma unroll
        for (int q = 1; q < 4; ++q) {
            float m2 = sm[t + 64 * q], z2 = sz[t + 64 * q];
            float mn = fmaxf(gm, m2);
            gz = gz * __expf(SCALE_ * (gm - mn)) + z2 * __expf(SCALE_ * (m2 - mn));
            gm = mn;
        }
        int ss = sg * 64 + t;
        pm[(b * 8 + ch) * 4096 + ss] = gm;
        pz[(b * 8 + ch) * 4096 + ss] = gz;
    }
}

// ---------------- K3b: combine partials -> Mg, 1/Z ----------------
__global__ void k_soft_combine(const float* __restrict__ pm, const float* __restrict__ pz,
                               float* __restrict__ Mg, float* __restrict__ Zinv) {
    int idx = blockIdx.x * 256 + threadIdx.x;  // B*S
    if (idx >= B_ * S_) return;
    int b = idx >> 12, s = idx & 4095;
    float gm = -3.0e38f;
#pragma unroll
    for (int c = 0; c < 8; ++c) gm = fmaxf(gm, pm[(b * 8 + c) * 4096 + s]);
    float gz = 0.f;
#pragma unroll
    for (int c = 0; c < 8; ++c)
        gz += pz[(b * 8 + c) * 4096 + s] * __expf(SCALE_ * (pm[(b * 8 + c) * 4096 + s] - gm));
    Mg[idx] = gm;
    Zinv[idx] = 1.0f / gz;
}

// ---------------- K3c: write normalized softmax as bf16 (diag fused) ----------------
__global__ void k_soft_norm(const float* __restrict__ scores, const float* __restrict__ maskedf,
                            const float* __restrict__ Mg, const float* __restrict__ Zinv,
                            __hip_bfloat16* __restrict__ soft) {
    size_t idx = (size_t)blockIdx.x * 256 + threadIdx.x;  // B*L*S
    int s = (int)(idx & 4095);
    int l = (int)((idx >> 12) & 4095);
    int b = (int)(idx >> 24);
    const float* inb = scores + ((size_t)b << 24);
    float v = (maskedf[b * L_ + l] != 0.f) ? -1000.f : diag9(inb, l, s);
    int bs = (b << 12) + s;
    soft[idx] = __float2bfloat16(__expf(SCALE_ * (v - Mg[bs])) * Zinv[bs]);
}

// ---------------- K4: materialize cols (4x4 bg patches, stride 2, pad 1) ----------------
__global__ void k_cols(const float* __restrict__ bgfull, float* __restrict__ cols) {
    int idx = blockIdx.x * 256 + threadIdx.x;  // B*L*NCOL
    if (idx >= B_ * L_ * NCOL) return;
    int n = idx & 1023, l = (idx >> 10) & 4095, b = idx >> 22;
    int kj = n & 3, ki = (n >> 2) & 3, c = n >> 4;
    int lh = l >> 6, lw = l & 63;
    int y = 2 * lh + ki - 1, x = 2 * lw + kj - 1;
    float v = 0.f;
    if (y >= 0 && y < H_ && x >= 0 && x < W_) v = bgfull[((b * C_ + c) * H_ + y) * W_ + x];
    cols[idx] = v;
}

// ---------------- K5: deconv GEMM: patchT[b,s,n] = sum_l soft[b,l,s]*cols[b,l,n] ----------------
__global__ __launch_bounds__(256) void k_gemm2(const __hip_bfloat16* __restrict__ soft,
                                               const float* __restrict__ cols,
                                               float* __restrict__ patchT) {
    __shared__ float As[16][64];
    __shared__ float Bs[16][64];
    int t = threadIdx.x;
    int tx = t & 15, ty = t >> 4;
    int n0 = blockIdx.x * 64;  // 16 tiles
    int sT = blockIdx.y;       // 64 tiles
    int b = blockIdx.z;
    int kk = t >> 4, col0 = (t & 15) * 4;
    float acc[4][4] = {};
    for (int lt = 0; lt < L_; lt += 16) {
        int l = lt + kk;
        size_t arow = ((size_t)(b * L_ + l) << 12) + sT * 64;
        size_t brow = ((size_t)(b * L_ + l) << 10) + n0;
#pragma unroll
        for (int u = 0; u < 4; ++u) {
            As[kk][col0 + u] = __bfloat162float(soft[arow + col0 + u]);
            Bs[kk][col0 + u] = cols[brow + col0 + u];
        }
        __syncthreads();
#pragma unroll
        for (int kki = 0; kki < 16; ++kki) {
            float a[4], bb[4];
#pragma unroll
            for (int i = 0; i < 4; ++i) a[i] = As[kki][ty * 4 + i];
#pragma unroll
            for (int j = 0; j < 4; ++j) bb[j] = Bs[kki][tx * 4 + j];
#pragma unroll
            for (int i = 0; i < 4; ++i)
#pragma unroll
                for (int j = 0; j < 4; ++j) acc[i][j] = fmaf(a[i], bb[j], acc[i][j]);
        }
        __syncthreads();
    }
#pragma unroll
    for (int i = 0; i < 4; ++i) {
        int s = sT * 64 + ty * 4 + i;
        size_t base = ((size_t)(b * S_ + s) << 10) + n0 + tx * 4;
#pragma unroll
        for (int j = 0; j < 4; ++j) patchT[base + j] = acc[i][j];
    }
}

// ---------------- K6: overlap-add gather (col2im, stride 2, kernel 4, pad 1) ----------------
__global__ void k_col2im(const float* __restrict__ patchT, float* __restrict__ out) {
    int idx = blockIdx.x * 256 + threadIdx.x;  // B*C*H*W
    if (idx >= B_ * C_ * H_ * W_) return;
    int x = idx & 127, y = (idx >> 7) & 127, c = (idx >> 14) & 63, b = idx >> 20;
    float acc = 0.f;
    int ki0 = (y + 1) & 1, kj0 = (x + 1) & 1;
#pragma unroll
    for (int ki = ki0; ki < 4; ki += 2) {
        int i = (y + 1 - ki) >> 1;
        if (i < 0 || i >= HS) continue;
#pragma unroll
        for (int kj = kj0; kj < 4; kj += 2) {
            int j = (x + 1 - kj) >> 1;
            if (j < 0 || j >= WS) continue;
            acc += patchT[((size_t)(b * S_ + i * 64 + j) << 10) + c * 16 + ki * 4 + kj];
        }
    }
    out[idx] = acc;
}

extern "C" void kernel_launch(void* const* d_in, const int* in_sizes, int n_in,
                              void* d_out, int out_size, void* d_ws, size_t ws_size,
                              hipStream_t stream) {
    (void)in_sizes; (void)n_in; (void)out_size; (void)ws_size;
    const float* fg = (const float*)d_in[0];
    const float* bg = (const float*)d_in[1];
    const float* mask = (const float*)d_in[2];
    float* out = (float*)d_out;

    // ---- workspace layout (floats), total 51,544,064 f = 196.6 MiB ----
    float* ws = (float*)d_ws;
    float* scores = ws;                          // 33,554,432 f (B*L*S fp32)
    __hip_bfloat16* soft = (__hip_bfloat16*)(ws + 33554432);  // 33,554,432 bf16 = 16,777,216 f
    float* smalls = ws + 33554432 + 16777216;
    float* fg_ds = smalls;                       // 524,288
    float* bg_ds = fg_ds + 524288;               // 524,288
    float* m_ds = bg_ds + 524288;                // 8,192
    float* denom_inv = m_ds + 8192;              // 8,192
    float* maskedf = denom_inv + 8192;           // 8,192
    float* Mg = maskedf + 8192;                  // 8,192
    float* Zinv = Mg + 8192;                     // 8,192
    float* pm = Zinv + 8192;                     // 65,536
    float* pz = pm + 65536;                      // 65,536
    // aliases into scores region (dead after k_soft_norm):
    float* cols = scores;                        // 8,388,608 f
    float* patchT = scores + 8388608;            // 8,388,608 f

    k_downsample<<<(B_ * C_ * HS * WS + 255) / 256, 256, 0, stream>>>(fg, bg, mask, fg_ds, bg_ds, m_ds);
    k_patch_stats<<<(B_ * L_ + 255) / 256, 256, 0, stream>>>(bg_ds, m_ds, denom_inv, maskedf);

    dim3 g1(64, 64, B_);
    k_gemm1<<<g1, 256, 0, stream>>>(fg_ds, bg_ds, denom_inv, scores);

    dim3 g3(64, 8, B_);
    k_soft_part<<<g3, 256, 0, stream>>>(scores, maskedf, pm, pz);
    k_soft_combine<<<(B_ * S_ + 255) / 256, 256, 0, stream>>>(pm, pz, Mg, Zinv);
    k_soft_norm<<<(B_ * L_ * S_) / 256, 256, 0, stream>>>(scores, maskedf, Mg, Zinv, soft);

    k_cols<<<(B_ * L_ * NCOL + 255) / 256, 256, 0, stream>>>(bg, cols);

    dim3 g5(16, 64, B_);
    k_gemm2<<<g5, 256, 0, stream>>>(soft, cols, patchT);

    k_col2im<<<(B_ * C_ * H_ * W_ + 255) / 256, 256, 0, stream>>>(patchT, out);
}

// Round 3
// 1289.046 us; speedup vs baseline: 1.6388x; 1.6388x over previous
//
#include <hip/hip_runtime.h>
#include <hip/hip_bf16.h>

#define B_ 2
#define C_ 64
#define H_ 128
#define W_ 128
#define HS 64
#define WS 64
#define L_ 4096
#define S_ 4096
#define K1_ 576    // C*3*3
#define NCOL 1024  // C*4*4
#define SCALE_ 10.0f

typedef __attribute__((ext_vector_type(8))) short bf16x8;
typedef __attribute__((ext_vector_type(4))) float f32x4;

// async global->LDS, 16B per lane. LDS dest must be wave-uniform base; lane i
// lands at base + i*16B (guide §5: wave-uniform base + lane*size).
__device__ __forceinline__ void async_copy16(const void* gsrc, void* ldst) {
    __builtin_amdgcn_global_load_lds(
        (__attribute__((address_space(1))) const void*)gsrc,
        (__attribute__((address_space(3))) void*)ldst, 16, 0, 0);
}

// transposed flat index within a 64x64 grid
__device__ __forceinline__ int TT(int x) { return ((x & 63) << 6) | (x >> 6); }

// fused diag_prop -> T -> diag_prop -> T, evaluated pointwise from raw scores (single batch)
__device__ __forceinline__ float diag9(const float* __restrict__ inb, int l, int s) {
    int tl = TT(l), ts = TT(s);
    float acc = 0.f;
#pragma unroll
    for (int d2 = -1; d2 <= 1; ++d2) {
        int p = tl + d2, q = ts + d2;
        if (p < 0 || p >= 4096 || q < 0 || q >= 4096) continue;
        int l2 = TT(p), s2 = TT(q);
#pragma unroll
        for (int d1 = -1; d1 <= 1; ++d1) {
            int a = l2 + d1, c2 = s2 + d1;
            if (a >= 0 && a < 4096 && c2 >= 0 && c2 < 4096) acc += inb[((size_t)a << 12) + c2];
        }
    }
    return acc;
}

// ---------------- K0a: downsample fg/bg/mask by 2 ----------------
__global__ void k_downsample(const float* __restrict__ fg, const float* __restrict__ bg,
                             const float* __restrict__ mask,
                             float* __restrict__ fg_ds, float* __restrict__ bg_ds,
                             float* __restrict__ m_ds) {
    int idx = blockIdx.x * 256 + threadIdx.x;  // B*C*64*64
    if (idx >= B_ * C_ * HS * WS) return;
    int j = idx & 63, i = (idx >> 6) & 63, c = (idx >> 12) & 63, b = idx >> 18;
    int src = ((b * C_ + c) * H_ + 2 * i) * W_ + 2 * j;
    fg_ds[idx] = fg[src];
    bg_ds[idx] = bg[src];
    if (c == 0) m_ds[(b * HS + i) * WS + j] = mask[(b * H_ + 2 * i) * W_ + 2 * j];
}

// ---------------- K0b: per-pixel channel sum of squares ----------------
__global__ void k_sumsq(const float* __restrict__ bg_ds, float* __restrict__ ssq) {
    int idx = blockIdx.x * 256 + threadIdx.x;  // B*64*64
    if (idx >= B_ * HS * WS) return;
    int pix = idx & 4095, b = idx >> 12;
    float ss = 0.f;
    for (int c = 0; c < C_; ++c) {
        float v = bg_ds[((b * C_ + c) << 12) + pix];
        ss += v * v;
    }
    ssq[idx] = ss;
}

// ---------------- K0c: per-patch mask flag + 1/denom (3x3 box over ssq) ----------------
__global__ void k_patch_stats(const float* __restrict__ ssq, const float* __restrict__ m_ds,
                              float* __restrict__ denom_inv, float* __restrict__ maskedf) {
    int idx = blockIdx.x * 256 + threadIdx.x;  // B*L
    if (idx >= B_ * L_) return;
    int b = idx >> 12, l = idx & 4095, lh = l >> 6, lw = l & 63;
    float msum = 0.f, ss = 0.f;
    for (int di = -1; di <= 1; ++di)
        for (int dj = -1; dj <= 1; ++dj) {
            int i = lh + di, j = lw + dj;
            if (i >= 0 && i < HS && j >= 0 && j < WS) {
                msum += m_ds[(b * HS + i) * WS + j];
                ss += ssq[(b * HS + i) * WS + j];
            }
        }
    maskedf[idx] = (msum == 0.0f) ? 1.0f : 0.0f;
    denom_inv[idx] = 1.0f / fmaxf(sqrtf(ss), 0.001f);
}

// ---------------- K0d: im2col (3x3, pad 1) -> hi/lo bf16 split, [b][l][576] ----------------
__global__ void k_im2col(const float* __restrict__ src, __hip_bfloat16* __restrict__ hi,
                         __hip_bfloat16* __restrict__ lo) {
    int idx = blockIdx.x * 256 + threadIdx.x;  // B*L*576, k fastest
    int k = idx % K1_;
    int bl = idx / K1_;
    int l = bl & 4095, b = bl >> 12;
    int c = k / 9, r = k - 9 * c;
    int r3 = r / 3;
    int di = r3 - 1, dj = r - 3 * r3 - 1;
    int i = (l >> 6) + di, j = (l & 63) + dj;
    float v = 0.f;
    if (i >= 0 && i < HS && j >= 0 && j < WS) v = src[((b * C_ + c) << 12) + (i << 6) + j];
    __hip_bfloat16 h = __float2bfloat16(v);
    hi[idx] = h;
    lo[idx] = __float2bfloat16(v - __bfloat162float(h));
}

// ---------------- K1: scores GEMM, split-bf16 MFMA (fp32-equivalent) ----------------
// scores[l][s] = dinv[l] * sum_k bgcol[l][k]*fgcol[s][k], K=576
__global__ __launch_bounds__(256) void k_gemm1_mfma(const __hip_bfloat16* __restrict__ Ahi,
                                                    const __hip_bfloat16* __restrict__ Alo,
                                                    const __hip_bfloat16* __restrict__ Bhi,
                                                    const __hip_bfloat16* __restrict__ Blo,
                                                    const float* __restrict__ dinv,
                                                    float* __restrict__ scores) {
    __shared__ __hip_bfloat16 AsH[128 * 32], AsL[128 * 32], BsH[128 * 32], BsL[128 * 32];
    int t = threadIdx.x, lane = t & 63, w = t >> 6;
    int wm = w & 1, wn = w >> 1;
    int M0 = blockIdx.y * 128, N0 = blockIdx.x * 128;
    int srow = lane >> 2, schunk = (lane & 3) * 8;
    f32x4 acc[4][4] = {};
    for (int k0 = 0; k0 < K1_; k0 += 32) {
#pragma unroll
        for (int q = 0; q < 2; ++q) {
            int r = q * 64 + w * 16;
            size_t ga = (size_t)(M0 + r + srow) * K1_ + k0 + schunk;
            size_t gb = (size_t)(N0 + r + srow) * K1_ + k0 + schunk;
            int lo_ = r * 32;
            async_copy16(Ahi + ga, &AsH[lo_]);
            async_copy16(Alo + ga, &AsL[lo_]);
            async_copy16(Bhi + gb, &BsH[lo_]);
            async_copy16(Blo + gb, &BsL[lo_]);
        }
        __syncthreads();
        int q8 = (lane >> 4) * 8, mr = lane & 15;
        bf16x8 ah[4], al[4], bh[4], bl[4];
#pragma unroll
        for (int i = 0; i < 4; ++i) {
            int ra = (wm * 64 + i * 16 + mr) * 32 + q8;
            int rb = (wn * 64 + i * 16 + mr) * 32 + q8;
            ah[i] = *(const bf16x8*)&AsH[ra];
            al[i] = *(const bf16x8*)&AsL[ra];
            bh[i] = *(const bf16x8*)&BsH[rb];
            bl[i] = *(const bf16x8*)&BsL[rb];
        }
#pragma unroll
        for (int mt = 0; mt < 4; ++mt)
#pragma unroll
            for (int nt = 0; nt < 4; ++nt) {
                acc[mt][nt] = __builtin_amdgcn_mfma_f32_16x16x32_bf16(ah[mt], bh[nt], acc[mt][nt], 0, 0, 0);
                acc[mt][nt] = __builtin_amdgcn_mfma_f32_16x16x32_bf16(ah[mt], bl[nt], acc[mt][nt], 0, 0, 0);
                acc[mt][nt] = __builtin_amdgcn_mfma_f32_16x16x32_bf16(al[mt], bh[nt], acc[mt][nt], 0, 0, 0);
            }
        __syncthreads();
    }
    int col = lane & 15, rq = (lane >> 4) * 4;
#pragma unroll
    for (int mt = 0; mt < 4; ++mt)
#pragma unroll
        for (int r = 0; r < 4; ++r) {
            int m = M0 + wm * 64 + mt * 16 + rq + r;
            float dv = dinv[m];
#pragma unroll
            for (int nt = 0; nt < 4; ++nt) {
                int n = N0 + wn * 64 + nt * 16 + col;
                scores[(size_t)m * 4096 + n] = acc[mt][nt][r] * dv;
            }
        }
}

// ---------------- K3a: chunked online-softmax partials over l (diag fused, single batch) ----
__global__ __launch_bounds__(256) void k_soft_part(const float* __restrict__ scores,
                                                   const float* __restrict__ maskedf,
                                                   float* __restrict__ pm, float* __restrict__ pz) {
    __shared__ float sm[256], sz[256];
    int t = threadIdx.x;
    int tx = t & 63, tyy = t >> 6;
    int sg = blockIdx.x, ch = blockIdx.y;
    int s = sg * 64 + tx;
    float m = -3.0e38f, Z = 0.f;
    int l0 = ch * 512 + tyy;
    for (int ii = 0; ii < 128; ++ii) {
        int l = l0 + 4 * ii;
        float v = (maskedf[l] != 0.f) ? -1000.f : diag9(scores, l, s);
        float mn = fmaxf(m, v);
        Z = Z * __expf(SCALE_ * (m - mn)) + __expf(SCALE_ * (v - mn));
        m = mn;
    }
    sm[t] = m;
    sz[t] = Z;
    __syncthreads();
    if (t < 64) {
        float gm = sm[t], gz = sz[t];
#pragma unroll
        for (int q = 1; q < 4; ++q) {
            float m2 = sm[t + 64 * q], z2 = sz[t + 64 * q];
            float mn = fmaxf(gm, m2);
            gz = gz * __expf(SCALE_ * (gm - mn)) + z2 * __expf(SCALE_ * (m2 - mn));
            gm = mn;
        }
        int ss = sg * 64 + t;
        pm[ch * 4096 + ss] = gm;
        pz[ch * 4096 + ss] = gz;
    }
}

// ---------------- K3b: combine partials -> Mg, 1/Z (single batch) ----------------
__global__ void k_soft_combine(const float* __restrict__ pm, const float* __restrict__ pz,
                               float* __restrict__ Mg, float* __restrict__ Zinv) {
    int s = blockIdx.x * 256 + threadIdx.x;  // 4096
    if (s >= S_) return;
    float gm = -3.0e38f;
#pragma unroll
    for (int c = 0; c < 8; ++c) gm = fmaxf(gm, pm[c * 4096 + s]);
    float gz = 0.f;
#pragma unroll
    for (int c = 0; c < 8; ++c) gz += pz[c * 4096 + s] * __expf(SCALE_ * (pm[c * 4096 + s] - gm));
    Mg[s] = gm;
    Zinv[s] = 1.0f / gz;
}

// ---------------- K3c: normalized softmax, fused transpose, bf16 out [s][l] ----------------
__global__ __launch_bounds__(256) void k_soft_normT(const float* __restrict__ scores,
                                                    const float* __restrict__ maskedf,
                                                    const float* __restrict__ Mg,
                                                    const float* __restrict__ Zinv,
                                                    __hip_bfloat16* __restrict__ softT) {
    __shared__ float tile[64][65];
    int t = threadIdx.x;
    int sx = t & 63, tg = t >> 6;
    int s0 = blockIdx.x * 64, l0 = blockIdx.y * 64;
    int s = s0 + sx;
    float mg = Mg[s], zi = Zinv[s];
#pragma unroll
    for (int i = 0; i < 16; ++i) {
        int lloc = tg * 16 + i;
        int l = l0 + lloc;
        float v = (maskedf[l] != 0.f) ? -1000.f : diag9(scores, l, s);
        tile[lloc][sx] = __expf(SCALE_ * (v - mg)) * zi;
    }
    __syncthreads();
#pragma unroll
    for (int i = 0; i < 16; ++i) {
        int sloc = tg * 16 + i;
        softT[(size_t)(s0 + sloc) * 4096 + l0 + sx] = __float2bfloat16(tile[sx][sloc]);
    }
}

// ---------------- K4: cols_T[b][n][l] bf16 (4x4 bg patches, stride 2, pad 1) ----------------
__global__ void k_colsT(const float* __restrict__ bgfull, __hip_bfloat16* __restrict__ colsT) {
    int idx = blockIdx.x * 256 + threadIdx.x;  // B*NCOL*L, l fastest
    int l = idx & 4095, n = (idx >> 12) & 1023, b = idx >> 22;
    int kj = n & 3, ki = (n >> 2) & 3, c = n >> 4;
    int y = 2 * (l >> 6) + ki - 1, x = 2 * (l & 63) + kj - 1;
    float v = 0.f;
    if (y >= 0 && y < H_ && x >= 0 && x < W_) v = bgfull[((b * C_ + c) * H_ + y) * W_ + x];
    colsT[idx] = __float2bfloat16(v);
}

// ---------------- K5: deconv GEMM, bf16 MFMA: patchT[b][s][n] ----------------
__global__ __launch_bounds__(256) void k_gemm2_mfma(const __hip_bfloat16* __restrict__ softT,
                                                    const __hip_bfloat16* __restrict__ colsT,
                                                    float* __restrict__ patchT) {
    __shared__ __hip_bfloat16 As[128 * 32], Bs[128 * 32];
    int t = threadIdx.x, lane = t & 63, w = t >> 6;
    int wm = w & 1, wn = w >> 1;
    int N0 = blockIdx.x * 128, M0 = blockIdx.y * 128, b = blockIdx.z;
    const __hip_bfloat16* Ab = softT + ((size_t)b << 24);  // [4096][4096]
    const __hip_bfloat16* Bb = colsT + ((size_t)b << 22);  // [1024][4096]
    float* Db = patchT + ((size_t)b << 22);                // [4096][1024]
    int srow = lane >> 2, schunk = (lane & 3) * 8;
    f32x4 acc[4][4] = {};
    for (int k0 = 0; k0 < L_; k0 += 32) {
#pragma unroll
        for (int q = 0; q < 2; ++q) {
            int r = q * 64 + w * 16;
            async_copy16(Ab + (size_t)(M0 + r + srow) * 4096 + k0 + schunk, &As[r * 32]);
            async_copy16(Bb + (size_t)(N0 + r + srow) * 4096 + k0 + schunk, &Bs[r * 32]);
        }
        __syncthreads();
        int q8 = (lane >> 4) * 8, mr = lane & 15;
        bf16x8 af[4], bfr[4];
#pragma unroll
        for (int i = 0; i < 4; ++i) {
            af[i] = *(const bf16x8*)&As[(wm * 64 + i * 16 + mr) * 32 + q8];
            bfr[i] = *(const bf16x8*)&Bs[(wn * 64 + i * 16 + mr) * 32 + q8];
        }
#pragma unroll
        for (int mt = 0; mt < 4; ++mt)
#pragma unroll
            for (int nt = 0; nt < 4; ++nt)
                acc[mt][nt] = __builtin_amdgcn_mfma_f32_16x16x32_bf16(af[mt], bfr[nt], acc[mt][nt], 0, 0, 0);
        __syncthreads();
    }
    int col = lane & 15, rq = (lane >> 4) * 4;
#pragma unroll
    for (int mt = 0; mt < 4; ++mt)
#pragma unroll
        for (int r = 0; r < 4; ++r) {
            int m = M0 + wm * 64 + mt * 16 + rq + r;
#pragma unroll
            for (int nt = 0; nt < 4; ++nt) {
                int n = N0 + wn * 64 + nt * 16 + col;
                Db[(size_t)m * 1024 + n] = acc[mt][nt][r];
            }
        }
}

// ---------------- K6: overlap-add gather (col2im, stride 2, kernel 4, pad 1) ----------------
__global__ void k_col2im(const float* __restrict__ patchT, float* __restrict__ out) {
    int idx = blockIdx.x * 256 + threadIdx.x;  // B*C*H*W
    if (idx >= B_ * C_ * H_ * W_) return;
    int x = idx & 127, y = (idx >> 7) & 127, c = (idx >> 14) & 63, b = idx >> 20;
    float acc = 0.f;
    int ki0 = (y + 1) & 1, kj0 = (x + 1) & 1;
#pragma unroll
    for (int ki = ki0; ki < 4; ki += 2) {
        int i = (y + 1 - ki) >> 1;
        if (i < 0 || i >= HS) continue;
#pragma unroll
        for (int kj = kj0; kj < 4; kj += 2) {
            int j = (x + 1 - kj) >> 1;
            if (j < 0 || j >= WS) continue;
            acc += patchT[((size_t)(b * S_ + i * 64 + j) << 10) + c * 16 + ki * 4 + kj];
        }
    }
    out[idx] = acc;
}

extern "C" void kernel_launch(void* const* d_in, const int* in_sizes, int n_in,
                              void* d_out, int out_size, void* d_ws, size_t ws_size,
                              hipStream_t stream) {
    (void)in_sizes; (void)n_in; (void)out_size; (void)ws_size;
    const float* fg = (const float*)d_in[0];
    const float* bg = (const float*)d_in[1];
    const float* mask = (const float*)d_in[2];
    float* out = (float*)d_out;

    // ---- workspace layout (float offsets), total 48,340,992 f = 193.4 MiB ----
    float* ws = (float*)d_ws;
    __hip_bfloat16* soft_T = (__hip_bfloat16*)ws;                    // 33,554,432 bf16
    __hip_bfloat16* cols_T = (__hip_bfloat16*)(ws + 16777216);       // 8,388,608 bf16
    __hip_bfloat16* bgcol_hi = (__hip_bfloat16*)(ws + 20971520);     // 4,718,592 bf16
    __hip_bfloat16* bgcol_lo = (__hip_bfloat16*)(ws + 23330816);
    __hip_bfloat16* fgcol_hi = (__hip_bfloat16*)(ws + 25690112);
    __hip_bfloat16* fgcol_lo = (__hip_bfloat16*)(ws + 28049408);
    float* fg_ds = ws + 30408704;      // 524,288
    float* bg_ds = ws + 30932992;      // 524,288
    float* m_ds = ws + 31457280;       // 8,192
    float* denom_inv = ws + 31465472;  // 8,192 (B*L)
    float* maskedf = ws + 31473664;    // 8,192 (B*L)
    float* ssq = ws + 31481856;        // 8,192
    float* Mg = ws + 31490048;         // 4,096 (per batch, reused)
    float* Zinv = ws + 31494144;       // 4,096
    float* pm = ws + 31498240;         // 32,768
    float* pz = ws + 31531008;         // 32,768
    float* scores = ws + 31563776;     // 16,777,216 (per-batch fp32)
    float* patchT = scores;            // alias: scores dead before gemm2

    k_downsample<<<(B_ * C_ * HS * WS) / 256, 256, 0, stream>>>(fg, bg, mask, fg_ds, bg_ds, m_ds);
    k_sumsq<<<(B_ * HS * WS) / 256, 256, 0, stream>>>(bg_ds, ssq);
    k_patch_stats<<<(B_ * L_) / 256, 256, 0, stream>>>(ssq, m_ds, denom_inv, maskedf);
    k_im2col<<<(B_ * L_ * K1_) / 256, 256, 0, stream>>>(bg_ds, bgcol_hi, bgcol_lo);
    k_im2col<<<(B_ * L_ * K1_) / 256, 256, 0, stream>>>(fg_ds, fgcol_hi, fgcol_lo);
    k_colsT<<<(B_ * NCOL * L_) / 256, 256, 0, stream>>>(bg, cols_T);

    for (int b = 0; b < B_; ++b) {
        size_t co = (size_t)b * L_ * K1_;
        dim3 g1(32, 32);
        k_gemm1_mfma<<<g1, 256, 0, stream>>>(bgcol_hi + co, bgcol_lo + co, fgcol_hi + co,
                                             fgcol_lo + co, denom_inv + b * L_, scores);
        dim3 g3(64, 8);
        k_soft_part<<<g3, 256, 0, stream>>>(scores, maskedf + b * L_, pm, pz);
        k_soft_combine<<<16, 256, 0, stream>>>(pm, pz, Mg, Zinv);
        dim3 g4(64, 64);
        k_soft_normT<<<g4, 256, 0, stream>>>(scores, maskedf + b * L_, Mg, Zinv,
                                             soft_T + ((size_t)b << 24));
    }

    dim3 g5(8, 32, B_);
    k_gemm2_mfma<<<g5, 256, 0, stream>>>(soft_T, cols_T, patchT);
    k_col2im<<<(B_ * C_ * H_ * W_) / 256, 256, 0, stream>>>(patchT, out);
}

// Round 4
// 764.473 us; speedup vs baseline: 2.7633x; 1.6862x over previous
//
#include <hip/hip_runtime.h>
#include <hip/hip_bf16.h>

#define B_ 2
#define C_ 64
#define H_ 128
#define W_ 128
#define HS 64
#define WS 64
#define L_ 4096
#define S_ 4096
#define K1_ 576    // C*3*3
#define NCOL 1024  // C*4*4
#define SCALE_ 10.0f

typedef __attribute__((ext_vector_type(8))) short bf16x8;
typedef __attribute__((ext_vector_type(4))) float f32x4;

// async global->LDS, 16B per lane (wave-uniform LDS base + lane*16).
__device__ __forceinline__ void async_copy16(const void* gsrc, void* ldst) {
    __builtin_amdgcn_global_load_lds(
        (__attribute__((address_space(1))) const void*)gsrc,
        (__attribute__((address_space(3))) void*)ldst, 16, 0, 0);
}

// transposed flat index within a 64x64 grid
__device__ __forceinline__ int TT(int x) { return ((x & 63) << 6) | (x >> 6); }

// fused diag_prop -> T -> diag_prop -> T, evaluated pointwise from raw scores (single batch)
__device__ __forceinline__ float diag9(const float* __restrict__ inb, int l, int s) {
    int tl = TT(l), ts = TT(s);
    float acc = 0.f;
#pragma unroll
    for (int d2 = -1; d2 <= 1; ++d2) {
        int p = tl + d2, q = ts + d2;
        if (p < 0 || p >= 4096 || q < 0 || q >= 4096) continue;
        int l2 = TT(p), s2 = TT(q);
#pragma unroll
        for (int d1 = -1; d1 <= 1; ++d1) {
            int a = l2 + d1, c2 = s2 + d1;
            if (a >= 0 && a < 4096 && c2 >= 0 && c2 < 4096) acc += inb[((size_t)a << 12) + c2];
        }
    }
    return acc;
}

// ---------------- K0a: per-pixel channel sum-of-squares of downsampled bg ----------------
__global__ void k_sumsq(const float* __restrict__ bg, float* __restrict__ ssq) {
    int idx = blockIdx.x * 256 + threadIdx.x;  // B*64*64
    if (idx >= B_ * HS * WS) return;
    int pix = idx & 4095, b = idx >> 12;
    int i = pix >> 6, j = pix & 63;
    float ss = 0.f;
    for (int c = 0; c < C_; ++c) {
        float v = bg[((b * C_ + c) * H_ + 2 * i) * W_ + 2 * j];
        ss += v * v;
    }
    ssq[idx] = ss;
}

// ---------------- K0b: per-patch mask flag + 1/denom (3x3 box) ----------------
__global__ void k_patch_stats(const float* __restrict__ mask, const float* __restrict__ ssq,
                              float* __restrict__ denom_inv, float* __restrict__ maskedf) {
    int idx = blockIdx.x * 256 + threadIdx.x;  // B*L
    if (idx >= B_ * L_) return;
    int b = idx >> 12, l = idx & 4095, lh = l >> 6, lw = l & 63;
    float msum = 0.f, ss = 0.f;
    for (int di = -1; di <= 1; ++di)
        for (int dj = -1; dj <= 1; ++dj) {
            int i = lh + di, j = lw + dj;
            if (i >= 0 && i < HS && j >= 0 && j < WS) {
                msum += mask[(b * H_ + 2 * i) * W_ + 2 * j];
                ss += ssq[(b << 12) + (i << 6) + j];
            }
        }
    maskedf[idx] = (msum == 0.0f) ? 1.0f : 0.0f;
    denom_inv[idx] = 1.0f / fmaxf(sqrtf(ss), 0.001f);
}

// ---------------- K0c: im2col (3x3, pad 1, on 2x-downsampled img) -> hi/lo bf16 [l][576] ----
__global__ void k_im2col(const float* __restrict__ src, __hip_bfloat16* __restrict__ hi,
                         __hip_bfloat16* __restrict__ lo) {
    int idx = blockIdx.x * 256 + threadIdx.x;  // L*576, k fastest
    int k = idx % K1_;
    int l = idx / K1_;
    int c = k / 9, r = k - 9 * c;
    int r3 = r / 3;
    int di = r3 - 1, dj = r - 3 * r3 - 1;
    int i = (l >> 6) + di, j = (l & 63) + dj;
    float v = 0.f;
    if (i >= 0 && i < HS && j >= 0 && j < WS) v = src[(c * H_ + 2 * i) * W_ + 2 * j];
    __hip_bfloat16 h = __float2bfloat16(v);
    hi[idx] = h;
    lo[idx] = __float2bfloat16(v - __bfloat162float(h));
}

// ---------------- K1: scores GEMM, split-bf16 MFMA (fp32-equivalent), single batch --------
__global__ __launch_bounds__(256) void k_gemm1_mfma(const __hip_bfloat16* __restrict__ Ahi,
                                                    const __hip_bfloat16* __restrict__ Alo,
                                                    const __hip_bfloat16* __restrict__ Bhi,
                                                    const __hip_bfloat16* __restrict__ Blo,
                                                    const float* __restrict__ dinv,
                                                    float* __restrict__ scores) {
    __shared__ __hip_bfloat16 AsH[128 * 32], AsL[128 * 32], BsH[128 * 32], BsL[128 * 32];
    int t = threadIdx.x, lane = t & 63, w = t >> 6;
    int wm = w & 1, wn = w >> 1;
    int M0 = blockIdx.y * 128, N0 = blockIdx.x * 128;
    int srow = lane >> 2, schunk = (lane & 3) * 8;
    f32x4 acc[4][4] = {};
    for (int k0 = 0; k0 < K1_; k0 += 32) {
#pragma unroll
        for (int q = 0; q < 2; ++q) {
            int r = q * 64 + w * 16;
            size_t ga = (size_t)(M0 + r + srow) * K1_ + k0 + schunk;
            size_t gb = (size_t)(N0 + r + srow) * K1_ + k0 + schunk;
            int lo_ = r * 32;
            async_copy16(Ahi + ga, &AsH[lo_]);
            async_copy16(Alo + ga, &AsL[lo_]);
            async_copy16(Bhi + gb, &BsH[lo_]);
            async_copy16(Blo + gb, &BsL[lo_]);
        }
        __syncthreads();
        int q8 = (lane >> 4) * 8, mr = lane & 15;
        bf16x8 ah[4], al[4], bh[4], bl[4];
#pragma unroll
        for (int i = 0; i < 4; ++i) {
            int ra = (wm * 64 + i * 16 + mr) * 32 + q8;
            int rb = (wn * 64 + i * 16 + mr) * 32 + q8;
            ah[i] = *(const bf16x8*)&AsH[ra];
            al[i] = *(const bf16x8*)&AsL[ra];
            bh[i] = *(const bf16x8*)&BsH[rb];
            bl[i] = *(const bf16x8*)&BsL[rb];
        }
#pragma unroll
        for (int mt = 0; mt < 4; ++mt)
#pragma unroll
            for (int nt = 0; nt < 4; ++nt) {
                acc[mt][nt] = __builtin_amdgcn_mfma_f32_16x16x32_bf16(ah[mt], bh[nt], acc[mt][nt], 0, 0, 0);
                acc[mt][nt] = __builtin_amdgcn_mfma_f32_16x16x32_bf16(ah[mt], bl[nt], acc[mt][nt], 0, 0, 0);
                acc[mt][nt] = __builtin_amdgcn_mfma_f32_16x16x32_bf16(al[mt], bh[nt], acc[mt][nt], 0, 0, 0);
            }
        __syncthreads();
    }
    int col = lane & 15, rq = (lane >> 4) * 4;
#pragma unroll
    for (int mt = 0; mt < 4; ++mt)
#pragma unroll
        for (int r = 0; r < 4; ++r) {
            int m = M0 + wm * 64 + mt * 16 + rq + r;
            float dv = dinv[m];
#pragma unroll
            for (int nt = 0; nt < 4; ++nt) {
                int n = N0 + wn * 64 + nt * 16 + col;
                scores[(size_t)m * 4096 + n] = acc[mt][nt][r] * dv;
            }
        }
}

// ---------------- K2: diag9 once -> D (masked), + chunked online-softmax partials ---------
// grid (16 s-tiles, 64 l-chunks), block 256. Thread owns one s, walks 64 l's.
__global__ __launch_bounds__(256) void k_diag_part(const float* __restrict__ scores,
                                                   const float* __restrict__ maskedf,
                                                   float* __restrict__ D,
                                                   float* __restrict__ pm, float* __restrict__ pz) {
    int s = blockIdx.x * 256 + threadIdx.x;
    int lc = blockIdx.y;
    float m = -3.0e38f, Z = 0.f;
    for (int i = 0; i < 64; ++i) {
        int l = (lc << 6) + i;
        float v = (maskedf[l] != 0.f) ? -1000.f : diag9(scores, l, s);
        D[((size_t)l << 12) + s] = v;
        float mn = fmaxf(m, v);
        Z = Z * __expf(SCALE_ * (m - mn)) + __expf(SCALE_ * (v - mn));
        m = mn;
    }
    pm[(lc << 12) + s] = m;
    pz[(lc << 12) + s] = Z;
}

// ---------------- K3: combine 64 partials -> Mg, 1/Z ----------------
__global__ void k_combine(const float* __restrict__ pm, const float* __restrict__ pz,
                          float* __restrict__ Mg, float* __restrict__ Zinv) {
    int s = blockIdx.x * 256 + threadIdx.x;  // 4096
    float gm = -3.0e38f;
    for (int c = 0; c < 64; ++c) gm = fmaxf(gm, pm[(c << 12) + s]);
    float gz = 0.f;
    for (int c = 0; c < 64; ++c) gz += pz[(c << 12) + s] * __expf(SCALE_ * (pm[(c << 12) + s] - gm));
    Mg[s] = gm;
    Zinv[s] = 1.0f / gz;
}

// ---------------- K4: normalize + transpose -> softT[s][l] bf16 (reads 1 tap of D) -------
__global__ __launch_bounds__(256) void k_soft_normT(const float* __restrict__ D,
                                                    const float* __restrict__ Mg,
                                                    const float* __restrict__ Zinv,
                                                    __hip_bfloat16* __restrict__ softT) {
    __shared__ float tile[64][65];
    int t = threadIdx.x;
    int sx = t & 63, tg = t >> 6;
    int s0 = blockIdx.x * 64, l0 = blockIdx.y * 64;
    int s = s0 + sx;
    float mg = Mg[s], zi = Zinv[s];
#pragma unroll
    for (int i = 0; i < 16; ++i) {
        int lloc = tg * 16 + i;
        float v = D[((size_t)(l0 + lloc) << 12) + s];
        tile[lloc][sx] = __expf(SCALE_ * (v - mg)) * zi;
    }
    __syncthreads();
#pragma unroll
    for (int i = 0; i < 16; ++i) {
        int sloc = tg * 16 + i;
        softT[((size_t)(s0 + sloc) << 12) + l0 + sx] = __float2bfloat16(tile[sx][sloc]);
    }
}

// ---------------- K5: cols_T[n][l] bf16 (4x4 bg patches, stride 2, pad 1), single batch ---
__global__ void k_colsT(const float* __restrict__ bgb, __hip_bfloat16* __restrict__ colsT) {
    int idx = blockIdx.x * 256 + threadIdx.x;  // NCOL*L, l fastest
    int l = idx & 4095, n = idx >> 12;
    int kj = n & 3, ki = (n >> 2) & 3, c = n >> 4;
    int y = 2 * (l >> 6) + ki - 1, x = 2 * (l & 63) + kj - 1;
    float v = 0.f;
    if (y >= 0 && y < H_ && x >= 0 && x < W_) v = bgb[(c * H_ + y) * W_ + x];
    colsT[idx] = __float2bfloat16(v);
}

// ---------------- K6: deconv GEMM, bf16 MFMA, 128x64 tiles: patchT[s][n], single batch ----
__global__ __launch_bounds__(256) void k_gemm2_mfma(const __hip_bfloat16* __restrict__ softT,
                                                    const __hip_bfloat16* __restrict__ colsT,
                                                    float* __restrict__ patchT) {
    __shared__ __hip_bfloat16 As[128 * 32], Bs[64 * 32];
    int t = threadIdx.x, lane = t & 63, w = t >> 6;
    int wm = w & 1, wn = w >> 1;
    int M0 = blockIdx.y * 128, N0 = blockIdx.x * 64;
    int srow = lane >> 2, schunk = (lane & 3) * 8;
    f32x4 acc[4][2] = {};
    for (int k0 = 0; k0 < L_; k0 += 32) {
#pragma unroll
        for (int q = 0; q < 2; ++q) {
            int r = q * 64 + w * 16;
            async_copy16(softT + ((size_t)(M0 + r + srow) << 12) + k0 + schunk, &As[r * 32]);
        }
        {
            int r = w * 16;
            async_copy16(colsT + ((size_t)(N0 + r + srow) << 12) + k0 + schunk, &Bs[r * 32]);
        }
        __syncthreads();
        int q8 = (lane >> 4) * 8, mr = lane & 15;
        bf16x8 af[4], bfr[2];
#pragma unroll
        for (int i = 0; i < 4; ++i) af[i] = *(const bf16x8*)&As[(wm * 64 + i * 16 + mr) * 32 + q8];
#pragma unroll
        for (int j = 0; j < 2; ++j) bfr[j] = *(const bf16x8*)&Bs[(wn * 32 + j * 16 + mr) * 32 + q8];
#pragma unroll
        for (int mt = 0; mt < 4; ++mt)
#pragma unroll
            for (int nt = 0; nt < 2; ++nt)
                acc[mt][nt] = __builtin_amdgcn_mfma_f32_16x16x32_bf16(af[mt], bfr[nt], acc[mt][nt], 0, 0, 0);
        __syncthreads();
    }
    int col = lane & 15, rq = (lane >> 4) * 4;
#pragma unroll
    for (int mt = 0; mt < 4; ++mt)
#pragma unroll
        for (int r = 0; r < 4; ++r) {
            int m = M0 + wm * 64 + mt * 16 + rq + r;
#pragma unroll
            for (int nt = 0; nt < 2; ++nt) {
                int n = N0 + wn * 32 + nt * 16 + col;
                patchT[(size_t)m * 1024 + n] = acc[mt][nt][r];
            }
        }
}

// ---------------- K7: overlap-add gather (col2im, stride 2, kernel 4, pad 1), single batch
__global__ void k_col2im(const float* __restrict__ patchT, float* __restrict__ outb) {
    int idx = blockIdx.x * 256 + threadIdx.x;  // C*H*W
    if (idx >= C_ * H_ * W_) return;
    int x = idx & 127, y = (idx >> 7) & 127, c = idx >> 14;
    float acc = 0.f;
    int ki0 = (y + 1) & 1, kj0 = (x + 1) & 1;
#pragma unroll
    for (int ki = ki0; ki < 4; ki += 2) {
        int i = (y + 1 - ki) >> 1;
        if (i < 0 || i >= HS) continue;
#pragma unroll
        for (int kj = kj0; kj < 4; kj += 2) {
            int j = (x + 1 - kj) >> 1;
            if (j < 0 || j >= WS) continue;
            acc += patchT[((size_t)(i * 64 + j) << 10) + c * 16 + ki * 4 + kj];
        }
    }
    outb[idx] = acc;
}

extern "C" void kernel_launch(void* const* d_in, const int* in_sizes, int n_in,
                              void* d_out, int out_size, void* d_ws, size_t ws_size,
                              hipStream_t stream) {
    (void)in_sizes; (void)n_in; (void)out_size; (void)ws_size;
    const float* fg = (const float*)d_in[0];
    const float* bg = (const float*)d_in[1];
    const float* mask = (const float*)d_in[2];
    float* out = (float*)d_out;

    // ---- workspace (float offsets), total 40,927,232 f = 156.1 MiB ----
    float* ws = (float*)d_ws;
    float* D = ws;                                               // 16,777,216
    float* scores = ws + 16777216;                               // 16,777,216
    __hip_bfloat16* softT = (__hip_bfloat16*)scores;             // alias (scores dead after k_diag_part)
    float* patchT = ws + 25165824;                               // alias, second half of scores region
    __hip_bfloat16* colsT = (__hip_bfloat16*)(ws + 33554432);    // 4,194,304 bf16
    __hip_bfloat16* bgcol_hi = (__hip_bfloat16*)(ws + 35651584); // 2,359,296 bf16 each
    __hip_bfloat16* bgcol_lo = (__hip_bfloat16*)(ws + 36831232);
    __hip_bfloat16* fgcol_hi = (__hip_bfloat16*)(ws + 38010880);
    __hip_bfloat16* fgcol_lo = (__hip_bfloat16*)(ws + 39190528);
    float* denom_inv = ws + 40370176;  // 8,192 (B*L)
    float* maskedf = ws + 40378368;    // 8,192 (B*L)
    float* ssq = ws + 40386560;        // 8,192
    float* Mg = ws + 40394752;         // 4,096
    float* Zinv = ws + 40398848;       // 4,096
    float* pm = ws + 40402944;         // 262,144
    float* pz = ws + 40665088;         // 262,144

    k_sumsq<<<(B_ * HS * WS) / 256, 256, 0, stream>>>(bg, ssq);
    k_patch_stats<<<(B_ * L_) / 256, 256, 0, stream>>>(mask, ssq, denom_inv, maskedf);

    for (int b = 0; b < B_; ++b) {
        const float* bgb = bg + (size_t)b * C_ * H_ * W_;
        const float* fgb = fg + (size_t)b * C_ * H_ * W_;

        k_im2col<<<(L_ * K1_) / 256, 256, 0, stream>>>(bgb, bgcol_hi, bgcol_lo);
        k_im2col<<<(L_ * K1_) / 256, 256, 0, stream>>>(fgb, fgcol_hi, fgcol_lo);
        k_colsT<<<(NCOL * L_) / 256, 256, 0, stream>>>(bgb, colsT);

        dim3 g1(32, 32);
        k_gemm1_mfma<<<g1, 256, 0, stream>>>(bgcol_hi, bgcol_lo, fgcol_hi, fgcol_lo,
                                             denom_inv + b * L_, scores);

        dim3 g2(16, 64);
        k_diag_part<<<g2, 256, 0, stream>>>(scores, maskedf + b * L_, D, pm, pz);
        k_combine<<<16, 256, 0, stream>>>(pm, pz, Mg, Zinv);
        dim3 g4(64, 64);
        k_soft_normT<<<g4, 256, 0, stream>>>(D, Mg, Zinv, softT);

        dim3 g5(16, 32);
        k_gemm2_mfma<<<g5, 256, 0, stream>>>(softT, colsT, patchT);
        k_col2im<<<(C_ * H_ * W_) / 256, 256, 0, stream>>>(patchT, out + (size_t)b * C_ * H_ * W_);
    }
}

// Round 5
// 754.546 us; speedup vs baseline: 2.7996x; 1.0132x over previous
//
#include <hip/hip_runtime.h>
#include <hip/hip_bf16.h>

#define B_ 2
#define C_ 64
#define H_ 128
#define W_ 128
#define HS 64
#define WS 64
#define L_ 4096
#define S_ 4096
#define K1_ 576    // C*3*3
#define NCOL 1024  // C*4*4
#define SCALE_ 10.0f

typedef __attribute__((ext_vector_type(8))) short bf16x8;
typedef __attribute__((ext_vector_type(4))) float f32x4;

// async global->LDS, 16B per lane (wave-uniform LDS base + lane*16).
__device__ __forceinline__ void async_copy16(const void* gsrc, void* ldst) {
    __builtin_amdgcn_global_load_lds(
        (__attribute__((address_space(1))) const void*)gsrc,
        (__attribute__((address_space(3))) void*)ldst, 16, 0, 0);
}

// transposed flat index within a 64x64 grid
__device__ __forceinline__ int TT(int x) { return ((x & 63) << 6) | (x >> 6); }

// fused diag_prop -> T -> diag_prop -> T, evaluated pointwise from raw scores (single batch)
__device__ __forceinline__ float diag9(const float* __restrict__ inb, int l, int s) {
    int tl = TT(l), ts = TT(s);
    float acc = 0.f;
#pragma unroll
    for (int d2 = -1; d2 <= 1; ++d2) {
        int p = tl + d2, q = ts + d2;
        if (p < 0 || p >= 4096 || q < 0 || q >= 4096) continue;
        int l2 = TT(p), s2 = TT(q);
#pragma unroll
        for (int d1 = -1; d1 <= 1; ++d1) {
            int a = l2 + d1, c2 = s2 + d1;
            if (a >= 0 && a < 4096 && c2 >= 0 && c2 < 4096) acc += inb[((size_t)a << 12) + c2];
        }
    }
    return acc;
}

// ---------------- K0a: per-pixel channel sum-of-squares of downsampled bg ----------------
__global__ void k_sumsq(const float* __restrict__ bg, float* __restrict__ ssq) {
    int idx = blockIdx.x * 256 + threadIdx.x;  // B*64*64
    if (idx >= B_ * HS * WS) return;
    int pix = idx & 4095, b = idx >> 12;
    int i = pix >> 6, j = pix & 63;
    float ss = 0.f;
    for (int c = 0; c < C_; ++c) {
        float v = bg[((b * C_ + c) * H_ + 2 * i) * W_ + 2 * j];
        ss += v * v;
    }
    ssq[idx] = ss;
}

// ---------------- K0b: per-patch mask flag + 1/denom (3x3 box) ----------------
__global__ void k_patch_stats(const float* __restrict__ mask, const float* __restrict__ ssq,
                              float* __restrict__ denom_inv, float* __restrict__ maskedf) {
    int idx = blockIdx.x * 256 + threadIdx.x;  // B*L
    if (idx >= B_ * L_) return;
    int b = idx >> 12, l = idx & 4095, lh = l >> 6, lw = l & 63;
    float msum = 0.f, ss = 0.f;
    for (int di = -1; di <= 1; ++di)
        for (int dj = -1; dj <= 1; ++dj) {
            int i = lh + di, j = lw + dj;
            if (i >= 0 && i < HS && j >= 0 && j < WS) {
                msum += mask[(b * H_ + 2 * i) * W_ + 2 * j];
                ss += ssq[(b << 12) + (i << 6) + j];
            }
        }
    maskedf[idx] = (msum == 0.0f) ? 1.0f : 0.0f;
    denom_inv[idx] = 1.0f / fmaxf(sqrtf(ss), 0.001f);
}

// ---------------- K0c: im2col (3x3, pad 1, on 2x-downsampled img) -> hi/lo bf16 [l][576] ----
__global__ void k_im2col(const float* __restrict__ src, __hip_bfloat16* __restrict__ hi,
                         __hip_bfloat16* __restrict__ lo) {
    int idx = blockIdx.x * 256 + threadIdx.x;  // L*576, k fastest
    int k = idx % K1_;
    int l = idx / K1_;
    int c = k / 9, r = k - 9 * c;
    int r3 = r / 3;
    int di = r3 - 1, dj = r - 3 * r3 - 1;
    int i = (l >> 6) + di, j = (l & 63) + dj;
    float v = 0.f;
    if (i >= 0 && i < HS && j >= 0 && j < WS) v = src[(c * H_ + 2 * i) * W_ + 2 * j];
    __hip_bfloat16 h = __float2bfloat16(v);
    hi[idx] = h;
    lo[idx] = __float2bfloat16(v - __bfloat162float(h));
}

// ---------------- K1: scores GEMM, split-bf16 MFMA (fp32-equivalent), single batch --------
__global__ __launch_bounds__(256) void k_gemm1_mfma(const __hip_bfloat16* __restrict__ Ahi,
                                                    const __hip_bfloat16* __restrict__ Alo,
                                                    const __hip_bfloat16* __restrict__ Bhi,
                                                    const __hip_bfloat16* __restrict__ Blo,
                                                    const float* __restrict__ dinv,
                                                    float* __restrict__ scores) {
    __shared__ __hip_bfloat16 AsH[128 * 32], AsL[128 * 32], BsH[128 * 32], BsL[128 * 32];
    int t = threadIdx.x, lane = t & 63, w = t >> 6;
    int wm = w & 1, wn = w >> 1;
    int M0 = blockIdx.y * 128, N0 = blockIdx.x * 128;
    int srow = lane >> 2, schunk = (lane & 3) * 8;
    f32x4 acc[4][4] = {};
    for (int k0 = 0; k0 < K1_; k0 += 32) {
#pragma unroll
        for (int q = 0; q < 2; ++q) {
            int r = q * 64 + w * 16;
            size_t ga = (size_t)(M0 + r + srow) * K1_ + k0 + schunk;
            size_t gb = (size_t)(N0 + r + srow) * K1_ + k0 + schunk;
            int lo_ = r * 32;
            async_copy16(Ahi + ga, &AsH[lo_]);
            async_copy16(Alo + ga, &AsL[lo_]);
            async_copy16(Bhi + gb, &BsH[lo_]);
            async_copy16(Blo + gb, &BsL[lo_]);
        }
        __syncthreads();
        int q8 = (lane >> 4) * 8, mr = lane & 15;
        bf16x8 ah[4], al[4], bh[4], bl[4];
#pragma unroll
        for (int i = 0; i < 4; ++i) {
            int ra = (wm * 64 + i * 16 + mr) * 32 + q8;
            int rb = (wn * 64 + i * 16 + mr) * 32 + q8;
            ah[i] = *(const bf16x8*)&AsH[ra];
            al[i] = *(const bf16x8*)&AsL[ra];
            bh[i] = *(const bf16x8*)&BsH[rb];
            bl[i] = *(const bf16x8*)&BsL[rb];
        }
#pragma unroll
        for (int mt = 0; mt < 4; ++mt)
#pragma unroll
            for (int nt = 0; nt < 4; ++nt) {
                acc[mt][nt] = __builtin_amdgcn_mfma_f32_16x16x32_bf16(ah[mt], bh[nt], acc[mt][nt], 0, 0, 0);
                acc[mt][nt] = __builtin_amdgcn_mfma_f32_16x16x32_bf16(ah[mt], bl[nt], acc[mt][nt], 0, 0, 0);
                acc[mt][nt] = __builtin_amdgcn_mfma_f32_16x16x32_bf16(al[mt], bh[nt], acc[mt][nt], 0, 0, 0);
            }
        __syncthreads();
    }
    int col = lane & 15, rq = (lane >> 4) * 4;
#pragma unroll
    for (int mt = 0; mt < 4; ++mt)
#pragma unroll
        for (int r = 0; r < 4; ++r) {
            int m = M0 + wm * 64 + mt * 16 + rq + r;
            float dv = dinv[m];
#pragma unroll
            for (int nt = 0; nt < 4; ++nt) {
                int n = N0 + wn * 64 + nt * 16 + col;
                scores[(size_t)m * 4096 + n] = acc[mt][nt][r] * dv;
            }
        }
}

// ---------------- K2: diag9 once -> D (masked), + per-chunk MAX only (no exp chain) ------
// grid (16 s-tiles, 64 l-chunks), block 256. Thread owns one s, walks 64 l's.
__global__ __launch_bounds__(256) void k_diag_part(const float* __restrict__ scores,
                                                   const float* __restrict__ maskedf,
                                                   float* __restrict__ D,
                                                   float* __restrict__ pm) {
    int s = blockIdx.x * 256 + threadIdx.x;
    int lc = blockIdx.y;
    float m = -3.0e38f;
    for (int i = 0; i < 64; ++i) {
        int l = (lc << 6) + i;
        float v = (maskedf[l] != 0.f) ? -1000.f : diag9(scores, l, s);
        D[((size_t)l << 12) + s] = v;
        m = fmaxf(m, v);
    }
    pm[(lc << 12) + s] = m;
}

// ---------------- K3: combine 64 partial maxes -> Mg ----------------
__global__ void k_combine(const float* __restrict__ pm, float* __restrict__ Mg) {
    int s = blockIdx.x * 256 + threadIdx.x;  // 4096
    float gm = -3.0e38f;
    for (int c = 0; c < 64; ++c) gm = fmaxf(gm, pm[(c << 12) + s]);
    Mg[s] = gm;
}

// ---------------- K4: exp + transpose -> softT[s][l] bf16 (UNNORMALIZED) + Z partials ----
__global__ __launch_bounds__(256) void k_soft_normT(const float* __restrict__ D,
                                                    const float* __restrict__ Mg,
                                                    __hip_bfloat16* __restrict__ softT,
                                                    float* __restrict__ pz) {
    __shared__ float tile[64][65];
    __shared__ float zpart[4][64];
    int t = threadIdx.x;
    int sx = t & 63, tg = t >> 6;
    int s0 = blockIdx.x * 64, l0 = blockIdx.y * 64;
    int s = s0 + sx;
    float mg = Mg[s];
    float zsum = 0.f;
#pragma unroll
    for (int i = 0; i < 16; ++i) {
        int lloc = tg * 16 + i;
        float v = D[((size_t)(l0 + lloc) << 12) + s];
        float e = __expf(SCALE_ * (v - mg));
        tile[lloc][sx] = e;
        zsum += e;
    }
    zpart[tg][sx] = zsum;
    __syncthreads();
    if (tg == 0) {
        float z = zpart[0][sx] + zpart[1][sx] + zpart[2][sx] + zpart[3][sx];
        pz[((size_t)(l0 >> 6) << 12) + s] = z;
    }
#pragma unroll
    for (int i = 0; i < 16; ++i) {
        int sloc = tg * 16 + i;
        softT[((size_t)(s0 + sloc) << 12) + l0 + sx] = __float2bfloat16(tile[sx][sloc]);
    }
}

// ---------------- K4b: Zinv[s] = 1 / sum of 64 Z partials ----------------
__global__ void k_zinv(const float* __restrict__ pz, float* __restrict__ Zinv) {
    int s = blockIdx.x * 256 + threadIdx.x;  // 4096
    float gz = 0.f;
    for (int c = 0; c < 64; ++c) gz += pz[(c << 12) + s];
    Zinv[s] = 1.0f / gz;
}

// ---------------- K5: cols_T[n][l] bf16 (4x4 bg patches, stride 2, pad 1), single batch ---
__global__ void k_colsT(const float* __restrict__ bgb, __hip_bfloat16* __restrict__ colsT) {
    int idx = blockIdx.x * 256 + threadIdx.x;  // NCOL*L, l fastest
    int l = idx & 4095, n = idx >> 12;
    int kj = n & 3, ki = (n >> 2) & 3, c = n >> 4;
    int y = 2 * (l >> 6) + ki - 1, x = 2 * (l & 63) + kj - 1;
    float v = 0.f;
    if (y >= 0 && y < H_ && x >= 0 && x < W_) v = bgb[(c * H_ + y) * W_ + x];
    colsT[idx] = __float2bfloat16(v);
}

// ---------------- K6: deconv GEMM, bf16 MFMA, 128x64 tiles; epilogue x Zinv[row] ----------
__global__ __launch_bounds__(256) void k_gemm2_mfma(const __hip_bfloat16* __restrict__ softT,
                                                    const __hip_bfloat16* __restrict__ colsT,
                                                    const float* __restrict__ Zinv,
                                                    float* __restrict__ patchT) {
    __shared__ __hip_bfloat16 As[128 * 32], Bs[64 * 32];
    int t = threadIdx.x, lane = t & 63, w = t >> 6;
    int wm = w & 1, wn = w >> 1;
    int M0 = blockIdx.y * 128, N0 = blockIdx.x * 64;
    int srow = lane >> 2, schunk = (lane & 3) * 8;
    f32x4 acc[4][2] = {};
    for (int k0 = 0; k0 < L_; k0 += 32) {
#pragma unroll
        for (int q = 0; q < 2; ++q) {
            int r = q * 64 + w * 16;
            async_copy16(softT + ((size_t)(M0 + r + srow) << 12) + k0 + schunk, &As[r * 32]);
        }
        {
            int r = w * 16;
            async_copy16(colsT + ((size_t)(N0 + r + srow) << 12) + k0 + schunk, &Bs[r * 32]);
        }
        __syncthreads();
        int q8 = (lane >> 4) * 8, mr = lane & 15;
        bf16x8 af[4], bfr[2];
#pragma unroll
        for (int i = 0; i < 4; ++i) af[i] = *(const bf16x8*)&As[(wm * 64 + i * 16 + mr) * 32 + q8];
#pragma unroll
        for (int j = 0; j < 2; ++j) bfr[j] = *(const bf16x8*)&Bs[(wn * 32 + j * 16 + mr) * 32 + q8];
#pragma unroll
        for (int mt = 0; mt < 4; ++mt)
#pragma unroll
            for (int nt = 0; nt < 2; ++nt)
                acc[mt][nt] = __builtin_amdgcn_mfma_f32_16x16x32_bf16(af[mt], bfr[nt], acc[mt][nt], 0, 0, 0);
        __syncthreads();
    }
    int col = lane & 15, rq = (lane >> 4) * 4;
#pragma unroll
    for (int mt = 0; mt < 4; ++mt)
#pragma unroll
        for (int r = 0; r < 4; ++r) {
            int m = M0 + wm * 64 + mt * 16 + rq + r;
            float zi = Zinv[m];
#pragma unroll
            for (int nt = 0; nt < 2; ++nt) {
                int n = N0 + wn * 32 + nt * 16 + col;
                patchT[(size_t)m * 1024 + n] = acc[mt][nt][r] * zi;
            }
        }
}

// ---------------- K7: overlap-add gather (col2im, stride 2, kernel 4, pad 1), single batch
__global__ void k_col2im(const float* __restrict__ patchT, float* __restrict__ outb) {
    int idx = blockIdx.x * 256 + threadIdx.x;  // C*H*W
    if (idx >= C_ * H_ * W_) return;
    int x = idx & 127, y = (idx >> 7) & 127, c = idx >> 14;
    float acc = 0.f;
    int ki0 = (y + 1) & 1, kj0 = (x + 1) & 1;
#pragma unroll
    for (int ki = ki0; ki < 4; ki += 2) {
        int i = (y + 1 - ki) >> 1;
        if (i < 0 || i >= HS) continue;
#pragma unroll
        for (int kj = kj0; kj < 4; kj += 2) {
            int j = (x + 1 - kj) >> 1;
            if (j < 0 || j >= WS) continue;
            acc += patchT[((size_t)(i * 64 + j) << 10) + c * 16 + ki * 4 + kj];
        }
    }
    outb[idx] = acc;
}

extern "C" void kernel_launch(void* const* d_in, const int* in_sizes, int n_in,
                              void* d_out, int out_size, void* d_ws, size_t ws_size,
                              hipStream_t stream) {
    (void)in_sizes; (void)n_in; (void)out_size; (void)ws_size;
    const float* fg = (const float*)d_in[0];
    const float* bg = (const float*)d_in[1];
    const float* mask = (const float*)d_in[2];
    float* out = (float*)d_out;

    // ---- workspace (float offsets), total 40,927,232 f = 156.1 MiB ----
    float* ws = (float*)d_ws;
    float* D = ws;                                               // 16,777,216
    float* scores = ws + 16777216;                               // 16,777,216
    __hip_bfloat16* softT = (__hip_bfloat16*)scores;             // alias (scores dead after k_diag_part)
    float* patchT = ws + 25165824;                               // alias, second half of scores region
    __hip_bfloat16* colsT = (__hip_bfloat16*)(ws + 33554432);    // 4,194,304 bf16
    __hip_bfloat16* bgcol_hi = (__hip_bfloat16*)(ws + 35651584); // 2,359,296 bf16 each
    __hip_bfloat16* bgcol_lo = (__hip_bfloat16*)(ws + 36831232);
    __hip_bfloat16* fgcol_hi = (__hip_bfloat16*)(ws + 38010880);
    __hip_bfloat16* fgcol_lo = (__hip_bfloat16*)(ws + 39190528);
    float* denom_inv = ws + 40370176;  // 8,192 (B*L)
    float* maskedf = ws + 40378368;    // 8,192 (B*L)
    float* ssq = ws + 40386560;        // 8,192
    float* Mg = ws + 40394752;         // 4,096
    float* Zinv = ws + 40398848;       // 4,096
    float* pm = ws + 40402944;         // 262,144
    float* pz = ws + 40665088;         // 262,144

    k_sumsq<<<(B_ * HS * WS) / 256, 256, 0, stream>>>(bg, ssq);
    k_patch_stats<<<(B_ * L_) / 256, 256, 0, stream>>>(mask, ssq, denom_inv, maskedf);

    for (int b = 0; b < B_; ++b) {
        const float* bgb = bg + (size_t)b * C_ * H_ * W_;
        const float* fgb = fg + (size_t)b * C_ * H_ * W_;

        k_im2col<<<(L_ * K1_) / 256, 256, 0, stream>>>(bgb, bgcol_hi, bgcol_lo);
        k_im2col<<<(L_ * K1_) / 256, 256, 0, stream>>>(fgb, fgcol_hi, fgcol_lo);
        k_colsT<<<(NCOL * L_) / 256, 256, 0, stream>>>(bgb, colsT);

        dim3 g1(32, 32);
        k_gemm1_mfma<<<g1, 256, 0, stream>>>(bgcol_hi, bgcol_lo, fgcol_hi, fgcol_lo,
                                             denom_inv + b * L_, scores);

        dim3 g2(16, 64);
        k_diag_part<<<g2, 256, 0, stream>>>(scores, maskedf + b * L_, D, pm);
        k_combine<<<16, 256, 0, stream>>>(pm, Mg);
        dim3 g4(64, 64);
        k_soft_normT<<<g4, 256, 0, stream>>>(D, Mg, softT, pz);
        k_zinv<<<16, 256, 0, stream>>>(pz, Zinv);

        dim3 g5(16, 32);
        k_gemm2_mfma<<<g5, 256, 0, stream>>>(softT, colsT, Zinv, patchT);
        k_col2im<<<(C_ * H_ * W_) / 256, 256, 0, stream>>>(patchT, out + (size_t)b * C_ * H_ * W_);
    }
}